// Round 6
// baseline (391.204 us; speedup 1.0000x reference)
//
#include <hip/hip_runtime.h>
#include <hip/hip_fp16.h>

typedef unsigned int uint32;

#define B_ 16
#define N_ 400
#define D_ 256
#define H_ 8
#define DH_ 32
#define NW_ 4

#if __has_builtin(__builtin_amdgcn_exp2f)
#define EXP2(x) __builtin_amdgcn_exp2f(x)
#else
#define EXP2(x) exp2f(x)
#endif

// log2(e)/sqrt(32): exp(|qk/sqrt(32) * w|) == exp2(|qk*SCL * w|)
#define QK_SCL 0.2550348f

using bf16x8 = __attribute__((ext_vector_type(8))) short;
using f16x8  = __attribute__((ext_vector_type(8))) _Float16;
using f16x4  = __attribute__((ext_vector_type(4))) _Float16;
using f32x4  = __attribute__((ext_vector_type(4))) float;

__device__ __forceinline__ ushort f2b(float f) {
  uint32 u = __float_as_uint(f);
  uint32 r = (u + 0x7fffu + ((u >> 16) & 1u)) >> 16;
  return (ushort)r;
}

// ---------------------------------------------------------------------------
// Convert fp32 inputs -> bf16 scratch copies (x + 6 weight matrices)
// ---------------------------------------------------------------------------
__global__ __launch_bounds__(256) void convert_kernel(
    const float* __restrict__ x,  const float* __restrict__ wq,
    const float* __restrict__ wk, const float* __restrict__ wv,
    const float* __restrict__ wo, const float* __restrict__ w1,
    const float* __restrict__ w2,
    ushort* __restrict__ xb,  ushort* __restrict__ wqb,
    ushort* __restrict__ wkb, ushort* __restrict__ wvb,
    ushort* __restrict__ wob, ushort* __restrict__ w1b,
    ushort* __restrict__ w2b) {
  int gid = blockIdx.x * 256 + threadIdx.x;   // unit = 4 floats
  const float* src; ushort* dst;
  if      (gid < 409600) { src = x;  dst = xb;  }
  else if ((gid -= 409600) < 16384) { src = wq; dst = wqb; }
  else if ((gid -= 16384) < 16384)  { src = wk; dst = wkb; }
  else if ((gid -= 16384) < 16384)  { src = wv; dst = wvb; }
  else if ((gid -= 16384) < 16384)  { src = wo; dst = wob; }
  else if ((gid -= 16384) < 65536)  { src = w1; dst = w1b; }
  else { gid -= 65536; src = w2; dst = w2b; }
  float4 f = ((const float4*)src)[gid];
  ushort4 u;
  u.x = f2b(f.x); u.y = f2b(f.y); u.z = f2b(f.z); u.w = f2b(f.w);
  *(ushort4*)&dst[(size_t)gid * 4] = u;
}

// ---------------------------------------------------------------------------
// Generic bf16 MFMA GEMM: C[M,N] = A[M,K] @ W[N,K]^T + bias, fused epilogue.
// 64x64 tile, 256 threads (4 waves), double-buffered LDS: 1 barrier / K-step.
// ---------------------------------------------------------------------------
template <int RELU, int RESID, int OUT_F32, int OUT_BF16>
__global__ __launch_bounds__(256) void gemm_bt(
    const ushort* __restrict__ A, const ushort* __restrict__ W,
    const float* __restrict__ bias, const float* __restrict__ resid,
    float* __restrict__ outf, ushort* __restrict__ outb,
    int M, int N, int K) {
  __shared__ __align__(16) ushort As[2][64 * 40];  // +8 bf16 pad per row
  __shared__ __align__(16) ushort Ws[2][64 * 40];
  int t = threadIdx.x;
  int l = t & 63, w = t >> 6;
  int n0 = blockIdx.x * 64, m0 = blockIdx.y * 64;
  int srow = t >> 2, sc = (t & 3) * 8;
  int lrow = l & 15, lk = (l >> 4) * 8;

  const uint4* ag = (const uint4*)&A[(size_t)(m0 + srow) * K + sc];
  const uint4* wg = (const uint4*)&W[(size_t)(n0 + srow) * K + sc];
  uint4 ar = ag[0], wr = wg[0];
  int nk = K >> 5;

  f32x4 acc[4];
#pragma unroll
  for (int nt = 0; nt < 4; nt++) acc[nt] = {0.f, 0.f, 0.f, 0.f};

  for (int kk = 0; kk < nk; kk++) {
    int cur = kk & 1;
    *(uint4*)&As[cur][srow * 40 + sc] = ar;
    *(uint4*)&Ws[cur][srow * 40 + sc] = wr;
    if (kk + 1 < nk) { ar = ag[(size_t)(kk + 1) * 4]; wr = wg[(size_t)(kk + 1) * 4]; }
    __syncthreads();
    bf16x8 af = *(const bf16x8*)&As[cur][(16 * w + lrow) * 40 + lk];
#pragma unroll
    for (int nt = 0; nt < 4; nt++) {
      bf16x8 bf = *(const bf16x8*)&Ws[cur][(nt * 16 + lrow) * 40 + lk];
      acc[nt] = __builtin_amdgcn_mfma_f32_16x16x32_bf16(af, bf, acc[nt], 0, 0, 0);
    }
  }

  // C/D layout: col = lane&15, row = (lane>>4)*4 + reg   [verified m89/m91]
#pragma unroll
  for (int nt = 0; nt < 4; nt++) {
    int n = n0 + nt * 16 + lrow;
    float bv = bias[n];
#pragma unroll
    for (int r = 0; r < 4; r++) {
      int m = m0 + 16 * w + (l >> 4) * 4 + r;
      float v = acc[nt][r] + bv;
      if (RELU)  v = fmaxf(v, 0.f);
      if (RESID) v += resid[(size_t)m * N + n];
      if (OUT_F32)  outf[(size_t)m * N + n] = v;
      if (OUT_BF16) outb[(size_t)m * N + n] = f2b(v);
    }
  }
}

// ---------------------------------------------------------------------------
// Fused QKV GEMM: one launch, z picks {q,k,v}. Same 64x64 MFMA core.
// q -> fp16 HEAD-MAJOR [b][h][m][32], pre-scaled by QK_SCL.
// k -> fp16 HEAD-MAJOR [b][h][m][32].
// v -> fp16 TRANSPOSED vt[b][d][m] (stride N_=400); d = h*32+dh.
// ---------------------------------------------------------------------------
__global__ __launch_bounds__(256) void qkv_gemm(
    const ushort* __restrict__ xb, const ushort* __restrict__ wq,
    const ushort* __restrict__ wk, const ushort* __restrict__ wv,
    const float* __restrict__ bq, const float* __restrict__ bk,
    const float* __restrict__ bv,
    _Float16* __restrict__ qh, _Float16* __restrict__ kh,
    _Float16* __restrict__ vt) {
  __shared__ __align__(16) ushort As[2][64 * 40];
  __shared__ __align__(16) ushort Ws[2][64 * 40];
  int z = blockIdx.z;
  const ushort* W = (z == 0) ? wq : (z == 1) ? wk : wv;
  const float* bias = (z == 0) ? bq : (z == 1) ? bk : bv;

  int t = threadIdx.x;
  int l = t & 63, w = t >> 6;
  int n0 = blockIdx.x * 64, m0 = blockIdx.y * 64;
  int srow = t >> 2, sc = (t & 3) * 8;
  int lrow = l & 15, lk = (l >> 4) * 8;

  const uint4* ag = (const uint4*)&xb[(size_t)(m0 + srow) * 256 + sc];
  const uint4* wg = (const uint4*)&W[(size_t)(n0 + srow) * 256 + sc];
  uint4 ar = ag[0], wr = wg[0];

  f32x4 acc[4];
#pragma unroll
  for (int nt = 0; nt < 4; nt++) acc[nt] = {0.f, 0.f, 0.f, 0.f};

  for (int kk = 0; kk < 8; kk++) {
    int cur = kk & 1;
    *(uint4*)&As[cur][srow * 40 + sc] = ar;
    *(uint4*)&Ws[cur][srow * 40 + sc] = wr;
    if (kk + 1 < 8) { ar = ag[(kk + 1) * 4]; wr = wg[(kk + 1) * 4]; }
    __syncthreads();
    bf16x8 af = *(const bf16x8*)&As[cur][(16 * w + lrow) * 40 + lk];
#pragma unroll
    for (int nt = 0; nt < 4; nt++) {
      bf16x8 bf = *(const bf16x8*)&Ws[cur][(nt * 16 + lrow) * 40 + lk];
      acc[nt] = __builtin_amdgcn_mfma_f32_16x16x32_bf16(af, bf, acc[nt], 0, 0, 0);
    }
  }

  int mb = m0 + 16 * w + (l >> 4) * 4;  // multiple of 4 -> never crosses b*400
  int bb = mb / 400;
  int mi = mb - bb * 400;
#pragma unroll
  for (int nt = 0; nt < 4; nt++) {
    int n = n0 + nt * 16 + lrow;
    float bvv = bias[n];
    if (z < 2) {
      _Float16* out = z ? kh : qh;
      float scl = z ? 1.f : QK_SCL;
      int hh = n >> 5, dd = n & 31;
      _Float16* dst = out + (((size_t)(bb * 8 + hh)) * 400 + mi) * 32 + dd;
#pragma unroll
      for (int r = 0; r < 4; r++)
        dst[(size_t)r * 32] = (_Float16)((acc[nt][r] + bvv) * scl);
    } else {
      _Float16 h4[4];
#pragma unroll
      for (int r = 0; r < 4; r++) h4[r] = (_Float16)(acc[nt][r] + bvv);
      *(uint2*)&vt[((size_t)bb * 256 + n) * 400 + mi] = *(uint2*)h4;
    }
  }
}

// ---------------------------------------------------------------------------
// Fused attention v7b: block = (b, 16 q-rows, 4 HEADS), 256 threads (4 waves).
// grid 800. LDS = 4 heads x [16][SP] fp16 = 53 KB -> 3 blocks/CU.
// Rationale (r4 post-mortem): v3/v6 at VGPR 32-36 serialized their aw loads
// (8 float4 in flight need 32 VGPRs alone) -> latency-bound at ~88us.
// v7 holds aw in registers (launch_bounds(256,3) -> ~170 VGPR budget),
// reuses each aw load for 4 heads (aw is head-invariant), prefetches the
// next row-group's aw during reduce/pass2, and recomputes exp2 in pass 2
// (no e storage; trans is only ~4us chip-wide per sweep).
// v7b: zero-init prefetch buffers + rotation guarded by g<3 (removes the
// indeterminate-value UB found in the r5 audit).
// XCD: the 2 head-group blocks of one (b,n0) share id%8 -> same XCD L2.
//   P1: S[h] = (Q_h*scl) @ K_h^T; tiles striped over waves, 4 heads' k-frags
//       in flight per tile.
//   P2: wave w owns rows n = 4g+w (g=0..3) for ALL 4 heads. Per g: 8 aw
//       float4 loads (regs), z[4h][4i] pass, 16 interleaved shfl chains,
//       pass-2 recompute -> scores fp32 + S fp16 overwrite.
//   P3b: wave w = head w: full 13-chunk S@V accumulation, direct store
//        (no cross-wave reduce, no extra barriers).
// ---------------------------------------------------------------------------
#define SP 416  // S row pitch in halves (832 B, 16B-aligned); 13 chunks of 32

__global__ __launch_bounds__(256, 3) void attn_kernel(
    const _Float16* __restrict__ qh, const _Float16* __restrict__ kh,
    const _Float16* __restrict__ vt, const float* __restrict__ aw,
    float* __restrict__ scores, ushort* __restrict__ attnb) {
  __shared__ __align__(16) __half S[4][16][SP];  // 53,248 B

  int id = blockIdx.x;
  int c = ((id >> 4) << 3) | (id & 7);  // 0..399: (b, n-tile) combo
  int hg = (id >> 3) & 1;               // head group: heads hg*4 .. hg*4+3
  int b = c / 25;
  int n0 = (c - b * 25) * 16;
  int h0 = hg * 4;

  int t = threadIdx.x;
  int w = t >> 6, l = t & 63;
  int lq = l >> 4, lr = l & 15;

  // ---- P1: S[h] = (Q_h*scl) @ K_h^T (tiles striped, 4 heads in flight) ----
  {
    const size_t bh8 = (size_t)b * 8 + h0;
    f16x8 af[4];
#pragma unroll
    for (int h = 0; h < 4; h++)
      af[h] = *(const f16x8*)(qh + ((bh8 + h) * 400 + n0 + lr) * 32 + lq * 8);
    for (int mt = w; mt < 25; mt += 4) {
      f16x8 bf[4];
#pragma unroll
      for (int h = 0; h < 4; h++)
        bf[h] = *(const f16x8*)(kh + ((bh8 + h) * 400 + mt * 16 + lr) * 32 + lq * 8);
#pragma unroll
      for (int h = 0; h < 4; h++) {
        f32x4 cc = {0.f, 0.f, 0.f, 0.f};
        cc = __builtin_amdgcn_mfma_f32_16x16x32_f16(af[h], bf[h], cc, 0, 0, 0);
#pragma unroll
        for (int r = 0; r < 4; r++)
          S[h][lq * 4 + r][mt * 16 + lr] = __float2half(cc[r]);
      }
    }
  }
  __syncthreads();

  // ---- P2: single aw sweep, aw in regs reused by 4 heads, g+1 prefetch ----
  {
    const float* awb = aw + (((size_t)(b * 4)) * 400 + n0) * 400;
    float* scb = scores + (((size_t)(b * 8 + h0)) * 400 + n0) * 400;
    int m0 = l * 4, m1 = 256 + l * 4;
    bool act = (l < 36);  // chunk1 covers m in [256,400) with 36 lanes

    float4 zf4 = {0.f, 0.f, 0.f, 0.f};
    float4 cA0[4] = {zf4, zf4, zf4, zf4};
    float4 cA1[4] = {zf4, zf4, zf4, zf4};
    float4 nA0[4] = {zf4, zf4, zf4, zf4};
    float4 nA1[4] = {zf4, zf4, zf4, zf4};
    {
      const float* awn = awb + (size_t)w * 400;  // g=0 row
#pragma unroll
      for (int i = 0; i < 4; i++)
        cA0[i] = *(const float4*)(awn + (size_t)i * 160000 + m0);
      if (act) {
#pragma unroll
        for (int i = 0; i < 4; i++)
          cA1[i] = *(const float4*)(awn + (size_t)i * 160000 + m1);
      }
    }

#pragma unroll 1
    for (int g = 0; g < 4; g++) {
      int n = g * 4 + w;  // wave-private row (n & 3 == w): no intra-P2 races
      // S fragments for all 4 heads
      f16x4 sh0[4], sh1[4];
#pragma unroll
      for (int h = 0; h < 4; h++) sh0[h] = *(const f16x4*)&S[h][n][m0];
#pragma unroll
      for (int h = 0; h < 4; h++)
        sh1[h] = act ? *(const f16x4*)&S[h][n][m1]
                     : f16x4{(_Float16)0.f, (_Float16)0.f,
                             (_Float16)0.f, (_Float16)0.f};

      // pass 1: z[h][i] per-lane partials (aw regs reused 4x across heads)
      float z[4][4];
#pragma unroll
      for (int h = 0; h < 4; h++) {
        float q0f[4], q1f[4];
#pragma unroll
        for (int j = 0; j < 4; j++) q0f[j] = (float)sh0[h][j];
#pragma unroll
        for (int j = 0; j < 4; j++) q1f[j] = (float)sh1[h][j];
#pragma unroll
        for (int i = 0; i < 4; i++) {
          float zz = 0.f;
#pragma unroll
          for (int j = 0; j < 4; j++)
            zz += EXP2(fabsf(q0f[j] * ((const float*)&cA0[i])[j]));
          if (act) {
#pragma unroll
            for (int j = 0; j < 4; j++)
              zz += EXP2(fabsf(q1f[j] * ((const float*)&cA1[i])[j]));
          }
          z[h][i] = zz;
        }
      }

      // prefetch aw for g+1 (hidden under reduce + pass 2)
      if (g < 3) {
        const float* awn = awb + (size_t)(n + 4) * 400;
#pragma unroll
        for (int i = 0; i < 4; i++)
          nA0[i] = *(const float4*)(awn + (size_t)i * 160000 + m0);
        if (act) {
#pragma unroll
          for (int i = 0; i < 4; i++)
            nA1[i] = *(const float4*)(awn + (size_t)i * 160000 + m1);
        }
      }

      // 16 interleaved 6-step reduce chains over the 64-lane wave
#pragma unroll
      for (int o = 1; o <= 32; o <<= 1)
#pragma unroll
        for (int h = 0; h < 4; h++)
#pragma unroll
          for (int i = 0; i < 4; i++)
            z[h][i] += __shfl_xor(z[h][i], o);

      // pass 2: recompute exp2 from the SAME aw regs; f32 accumulate
#pragma unroll
      for (int h = 0; h < 4; h++) {
        float zinv[4];
#pragma unroll
        for (int i = 0; i < 4; i++) zinv[i] = 0.25f / (z[h][i] + 1e-10f);
        float q0f[4];
#pragma unroll
        for (int j = 0; j < 4; j++) q0f[j] = (float)sh0[h][j];
        float o0[4] = {0.f, 0.f, 0.f, 0.f};
#pragma unroll
        for (int i = 0; i < 4; i++)
#pragma unroll
          for (int j = 0; j < 4; j++) {
            float tt = q0f[j] * ((const float*)&cA0[i])[j];
            o0[j] += copysignf(EXP2(fabsf(tt)) * zinv[i], tt);
          }
        float* scout = scb + (size_t)h * 160000 + (size_t)n * 400;
        float4 ov = {o0[0], o0[1], o0[2], o0[3]};
        *(float4*)(scout + m0) = ov;
        f16x4 hv;
#pragma unroll
        for (int j = 0; j < 4; j++) hv[j] = (_Float16)o0[j];
        *(f16x4*)&S[h][n][m0] = hv;
        if (act) {
          float q1f[4];
#pragma unroll
          for (int j = 0; j < 4; j++) q1f[j] = (float)sh1[h][j];
          float o1[4] = {0.f, 0.f, 0.f, 0.f};
#pragma unroll
          for (int i = 0; i < 4; i++)
#pragma unroll
            for (int j = 0; j < 4; j++) {
              float tt = q1f[j] * ((const float*)&cA1[i])[j];
              o1[j] += copysignf(EXP2(fabsf(tt)) * zinv[i], tt);
            }
          float4 ov1 = {o1[0], o1[1], o1[2], o1[3]};
          *(float4*)(scout + m1) = ov1;
          f16x4 hv1;
#pragma unroll
          for (int j = 0; j < 4; j++) hv1[j] = (_Float16)o1[j];
          *(f16x4*)&S[h][n][m1] = hv1;
        } else if (l < 40) {
          f16x4 hz;
#pragma unroll
          for (int j = 0; j < 4; j++) hz[j] = (_Float16)0.f;
          *(f16x4*)&S[h][n][m1] = hz;  // zero-pad cols 400..415 for PV
        }
      }

      // rotate prefetch buffers (only meaningful while prefetching)
      if (g < 3) {
#pragma unroll
        for (int i = 0; i < 4; i++) { cA0[i] = nA0[i]; cA1[i] = nA1[i]; }
      }
    }
  }
  __syncthreads();

  // ---- P3b: wave w = head w: O = S @ V, full accumulation, direct store ----
  {
    const _Float16* vbase = vt + (((size_t)b) * 256 + (h0 + w) * 32) * 400;
    const _Float16* Sh = (const _Float16*)&S[w][0][0];
    f32x4 a0 = {0.f, 0.f, 0.f, 0.f}, a1 = {0.f, 0.f, 0.f, 0.f};
    for (int c2 = 0; c2 < 13; c2++) {
      f16x8 sf = *(const f16x8*)(Sh + lr * SP + c2 * 32 + lq * 8);
      f16x8 v0 = *(const f16x8*)(vbase + (size_t)lr * 400 + c2 * 32 + lq * 8);
      f16x8 v1 = *(const f16x8*)(vbase + (size_t)(16 + lr) * 400 + c2 * 32 + lq * 8);
      a0 = __builtin_amdgcn_mfma_f32_16x16x32_f16(sf, v0, a0, 0, 0, 0);
      a1 = __builtin_amdgcn_mfma_f32_16x16x32_f16(sf, v1, a1, 0, 0, 0);
    }
    // C layout: row(n) = lq*4+r, col(d) = lr (a0) / 16+lr (a1)
#pragma unroll
    for (int r = 0; r < 4; r++) {
      size_t row = (size_t)(b * 400 + n0 + lq * 4 + r);
      attnb[row * 256 + (h0 + w) * 32 + lr]      = f2b(a0[r]);
      attnb[row * 256 + (h0 + w) * 32 + 16 + lr] = f2b(a1[r]);
    }
  }
}

// ---------------------------------------------------------------------------
// LayerNorm over last dim (256). One block per row.
// ---------------------------------------------------------------------------
__global__ __launch_bounds__(256) void ln_kernel(
    const float* __restrict__ src, const float* __restrict__ g,
    const float* __restrict__ be, float* __restrict__ outf,
    ushort* __restrict__ outb) {
  int row = blockIdx.x, t = threadIdx.x;
  float v = src[(size_t)row * 256 + t];
  __shared__ float red[4];
  float s = v;
#pragma unroll
  for (int o = 32; o > 0; o >>= 1) s += __shfl_down(s, o, 64);
  if ((t & 63) == 0) red[t >> 6] = s;
  __syncthreads();
  float mean = (red[0] + red[1] + red[2] + red[3]) * (1.f / 256.f);
  __syncthreads();
  float d = v - mean;
  s = d * d;
#pragma unroll
  for (int o = 32; o > 0; o >>= 1) s += __shfl_down(s, o, 64);
  if ((t & 63) == 0) red[t >> 6] = s;
  __syncthreads();
  float var = (red[0] + red[1] + red[2] + red[3]) * (1.f / 256.f);
  float y = d * rsqrtf(var + 1e-5f) * g[t] + be[t];
  outf[(size_t)row * 256 + t] = y;
  if (outb) outb[(size_t)row * 256 + t] = f2b(y);
}

// ---------------------------------------------------------------------------
extern "C" void kernel_launch(void* const* d_in, const int* in_sizes, int n_in,
                              void* d_out, int out_size, void* d_ws,
                              size_t ws_size, hipStream_t stream) {
  const float* x   = (const float*)d_in[0];
  const float* aw  = (const float*)d_in[1];
  const float* Wq  = (const float*)d_in[2];
  const float* bq  = (const float*)d_in[3];
  const float* Wk  = (const float*)d_in[4];
  const float* bk  = (const float*)d_in[5];
  const float* Wv  = (const float*)d_in[6];
  const float* bv  = (const float*)d_in[7];
  const float* Wo  = (const float*)d_in[8];
  const float* bo  = (const float*)d_in[9];
  const float* g1  = (const float*)d_in[10];
  const float* be1 = (const float*)d_in[11];
  const float* W1  = (const float*)d_in[12];
  const float* b1  = (const float*)d_in[13];
  const float* W2  = (const float*)d_in[14];
  const float* b2  = (const float*)d_in[15];
  const float* g2  = (const float*)d_in[16];
  const float* be2 = (const float*)d_in[17];

  if (ws_size < 34340864) return;  // scratch layout requirement

  char* ws = (char*)d_ws;
  ushort*   xb    = (ushort*)(ws + 0);          // 3,276,800
  ushort*   wqb   = (ushort*)(ws + 3276800);    //   131,072
  ushort*   wkb   = (ushort*)(ws + 3407872);
  ushort*   wvb   = (ushort*)(ws + 3538944);
  ushort*   wob   = (ushort*)(ws + 3670016);
  ushort*   w1b   = (ushort*)(ws + 3801088);    //   524,288
  ushort*   w2b   = (ushort*)(ws + 4325376);    //   524,288
  _Float16* qhb   = (_Float16*)(ws + 4849664);  // 3,276,800  [b][h][m][32]*scl
  _Float16* khb   = (_Float16*)(ws + 8126464);  //            [b][h][m][32]
  _Float16* vtb   = (_Float16*)(ws + 11403264); //            [b][d][m]
  ushort*   attnb = (ushort*)(ws + 14680064);
  float*    ao    = (float*)(ws + 17956864);    // 6,553,600 (reused as ffn2)
  float*    hbuf  = (float*)(ws + 24510464);    // 6,553,600
  ushort*   hb    = (ushort*)(ws + 31064064);   // 3,276,800 -> total 34,340,864
  ushort*   ffn1b = (ushort*)qhb;  // reuse q/k/v region, dead by then
  float*    ffn2  = ao;            // reuse ao, dead after LN1

  float* yout   = (float*)d_out;
  float* scores = yout + 1638400;

  convert_kernel<<<2368, 256, 0, stream>>>(x, Wq, Wk, Wv, Wo, W1, W2,
                                           xb, wqb, wkb, wvb, wob, w1b, w2b);
  qkv_gemm<<<dim3(4, 100, 3), 256, 0, stream>>>(
      xb, wqb, wkb, wvb, bq, bk, bv, qhb, khb, vtb);
  attn_kernel<<<800, 256, 0, stream>>>(qhb, khb, vtb, aw, scores, attnb);
  gemm_bt<0, 1, 1, 0><<<dim3(4, 100), 256, 0, stream>>>(
      attnb, wob, bo, x, ao, nullptr, 6400, 256, 256);
  ln_kernel<<<6400, 256, 0, stream>>>(ao, g1, be1, hbuf, hb);
  gemm_bt<1, 0, 0, 1><<<dim3(16, 100), 256, 0, stream>>>(
      hb, w1b, b1, nullptr, nullptr, ffn1b, 6400, 1024, 256);
  gemm_bt<0, 1, 1, 0><<<dim3(4, 100), 256, 0, stream>>>(
      ffn1b, w2b, b2, hbuf, ffn2, nullptr, 6400, 256, 1024);
  ln_kernel<<<6400, 256, 0, stream>>>(ffn2, g2, be2, yout, nullptr);
}

// Round 7
// 252.216 us; speedup vs baseline: 1.5511x; 1.5511x over previous
//
#include <hip/hip_runtime.h>
#include <hip/hip_fp16.h>

typedef unsigned int uint32;

#define B_ 16
#define N_ 400
#define D_ 256
#define H_ 8
#define DH_ 32
#define NW_ 4

#if __has_builtin(__builtin_amdgcn_exp2f)
#define EXP2(x) __builtin_amdgcn_exp2f(x)
#else
#define EXP2(x) exp2f(x)
#endif

// log2(e)/sqrt(32): exp(|qk/sqrt(32) * w|) == exp2(|qk*SCL * w|)
#define QK_SCL 0.2550348f

using bf16x8 = __attribute__((ext_vector_type(8))) short;
using f16x8  = __attribute__((ext_vector_type(8))) _Float16;
using f16x4  = __attribute__((ext_vector_type(4))) _Float16;
using f32x4  = __attribute__((ext_vector_type(4))) float;

__device__ __forceinline__ ushort f2b(float f) {
  uint32 u = __float_as_uint(f);
  uint32 r = (u + 0x7fffu + ((u >> 16) & 1u)) >> 16;
  return (ushort)r;
}

// ---------------------------------------------------------------------------
// Convert fp32 inputs -> bf16 scratch copies (x + 6 weight matrices)
// ---------------------------------------------------------------------------
__global__ __launch_bounds__(256) void convert_kernel(
    const float* __restrict__ x,  const float* __restrict__ wq,
    const float* __restrict__ wk, const float* __restrict__ wv,
    const float* __restrict__ wo, const float* __restrict__ w1,
    const float* __restrict__ w2,
    ushort* __restrict__ xb,  ushort* __restrict__ wqb,
    ushort* __restrict__ wkb, ushort* __restrict__ wvb,
    ushort* __restrict__ wob, ushort* __restrict__ w1b,
    ushort* __restrict__ w2b) {
  int gid = blockIdx.x * 256 + threadIdx.x;   // unit = 4 floats
  const float* src; ushort* dst;
  if      (gid < 409600) { src = x;  dst = xb;  }
  else if ((gid -= 409600) < 16384) { src = wq; dst = wqb; }
  else if ((gid -= 16384) < 16384)  { src = wk; dst = wkb; }
  else if ((gid -= 16384) < 16384)  { src = wv; dst = wvb; }
  else if ((gid -= 16384) < 16384)  { src = wo; dst = wob; }
  else if ((gid -= 16384) < 65536)  { src = w1; dst = w1b; }
  else { gid -= 65536; src = w2; dst = w2b; }
  float4 f = ((const float4*)src)[gid];
  ushort4 u;
  u.x = f2b(f.x); u.y = f2b(f.y); u.z = f2b(f.z); u.w = f2b(f.w);
  *(ushort4*)&dst[(size_t)gid * 4] = u;
}

// ---------------------------------------------------------------------------
// Generic bf16 MFMA GEMM: C[M,N] = A[M,K] @ W[N,K]^T + bias, fused epilogue.
// 64x64 tile, 256 threads (4 waves), double-buffered LDS: 1 barrier / K-step.
// ---------------------------------------------------------------------------
template <int RELU, int RESID, int OUT_F32, int OUT_BF16>
__global__ __launch_bounds__(256) void gemm_bt(
    const ushort* __restrict__ A, const ushort* __restrict__ W,
    const float* __restrict__ bias, const float* __restrict__ resid,
    float* __restrict__ outf, ushort* __restrict__ outb,
    int M, int N, int K) {
  __shared__ __align__(16) ushort As[2][64 * 40];  // +8 bf16 pad per row
  __shared__ __align__(16) ushort Ws[2][64 * 40];
  int t = threadIdx.x;
  int l = t & 63, w = t >> 6;
  int n0 = blockIdx.x * 64, m0 = blockIdx.y * 64;
  int srow = t >> 2, sc = (t & 3) * 8;
  int lrow = l & 15, lk = (l >> 4) * 8;

  const uint4* ag = (const uint4*)&A[(size_t)(m0 + srow) * K + sc];
  const uint4* wg = (const uint4*)&W[(size_t)(n0 + srow) * K + sc];
  uint4 ar = ag[0], wr = wg[0];
  int nk = K >> 5;

  f32x4 acc[4];
#pragma unroll
  for (int nt = 0; nt < 4; nt++) acc[nt] = {0.f, 0.f, 0.f, 0.f};

  for (int kk = 0; kk < nk; kk++) {
    int cur = kk & 1;
    *(uint4*)&As[cur][srow * 40 + sc] = ar;
    *(uint4*)&Ws[cur][srow * 40 + sc] = wr;
    if (kk + 1 < nk) { ar = ag[(size_t)(kk + 1) * 4]; wr = wg[(size_t)(kk + 1) * 4]; }
    __syncthreads();
    bf16x8 af = *(const bf16x8*)&As[cur][(16 * w + lrow) * 40 + lk];
#pragma unroll
    for (int nt = 0; nt < 4; nt++) {
      bf16x8 bf = *(const bf16x8*)&Ws[cur][(nt * 16 + lrow) * 40 + lk];
      acc[nt] = __builtin_amdgcn_mfma_f32_16x16x32_bf16(af, bf, acc[nt], 0, 0, 0);
    }
  }

  // C/D layout: col = lane&15, row = (lane>>4)*4 + reg   [verified m89/m91]
#pragma unroll
  for (int nt = 0; nt < 4; nt++) {
    int n = n0 + nt * 16 + lrow;
    float bv = bias[n];
#pragma unroll
    for (int r = 0; r < 4; r++) {
      int m = m0 + 16 * w + (l >> 4) * 4 + r;
      float v = acc[nt][r] + bv;
      if (RELU)  v = fmaxf(v, 0.f);
      if (RESID) v += resid[(size_t)m * N + n];
      if (OUT_F32)  outf[(size_t)m * N + n] = v;
      if (OUT_BF16) outb[(size_t)m * N + n] = f2b(v);
    }
  }
}

// ---------------------------------------------------------------------------
// Fused QKV GEMM: one launch, z picks {q,k,v}. Same 64x64 MFMA core.
// q -> fp16 HEAD-MAJOR [b][h][m][32], pre-scaled by QK_SCL.
// k -> fp16 HEAD-MAJOR [b][h][m][32].
// v -> fp16 TRANSPOSED vt[b][d][m] (stride N_=400); d = h*32+dh.
// ---------------------------------------------------------------------------
__global__ __launch_bounds__(256) void qkv_gemm(
    const ushort* __restrict__ xb, const ushort* __restrict__ wq,
    const ushort* __restrict__ wk, const ushort* __restrict__ wv,
    const float* __restrict__ bq, const float* __restrict__ bk,
    const float* __restrict__ bv,
    _Float16* __restrict__ qh, _Float16* __restrict__ kh,
    _Float16* __restrict__ vt) {
  __shared__ __align__(16) ushort As[2][64 * 40];
  __shared__ __align__(16) ushort Ws[2][64 * 40];
  int z = blockIdx.z;
  const ushort* W = (z == 0) ? wq : (z == 1) ? wk : wv;
  const float* bias = (z == 0) ? bq : (z == 1) ? bk : bv;

  int t = threadIdx.x;
  int l = t & 63, w = t >> 6;
  int n0 = blockIdx.x * 64, m0 = blockIdx.y * 64;
  int srow = t >> 2, sc = (t & 3) * 8;
  int lrow = l & 15, lk = (l >> 4) * 8;

  const uint4* ag = (const uint4*)&xb[(size_t)(m0 + srow) * 256 + sc];
  const uint4* wg = (const uint4*)&W[(size_t)(n0 + srow) * 256 + sc];
  uint4 ar = ag[0], wr = wg[0];

  f32x4 acc[4];
#pragma unroll
  for (int nt = 0; nt < 4; nt++) acc[nt] = {0.f, 0.f, 0.f, 0.f};

  for (int kk = 0; kk < 8; kk++) {
    int cur = kk & 1;
    *(uint4*)&As[cur][srow * 40 + sc] = ar;
    *(uint4*)&Ws[cur][srow * 40 + sc] = wr;
    if (kk + 1 < 8) { ar = ag[(kk + 1) * 4]; wr = wg[(kk + 1) * 4]; }
    __syncthreads();
    bf16x8 af = *(const bf16x8*)&As[cur][(16 * w + lrow) * 40 + lk];
#pragma unroll
    for (int nt = 0; nt < 4; nt++) {
      bf16x8 bf = *(const bf16x8*)&Ws[cur][(nt * 16 + lrow) * 40 + lk];
      acc[nt] = __builtin_amdgcn_mfma_f32_16x16x32_bf16(af, bf, acc[nt], 0, 0, 0);
    }
  }

  int mb = m0 + 16 * w + (l >> 4) * 4;  // multiple of 4 -> never crosses b*400
  int bb = mb / 400;
  int mi = mb - bb * 400;
#pragma unroll
  for (int nt = 0; nt < 4; nt++) {
    int n = n0 + nt * 16 + lrow;
    float bvv = bias[n];
    if (z < 2) {
      _Float16* out = z ? kh : qh;
      float scl = z ? 1.f : QK_SCL;
      int hh = n >> 5, dd = n & 31;
      _Float16* dst = out + (((size_t)(bb * 8 + hh)) * 400 + mi) * 32 + dd;
#pragma unroll
      for (int r = 0; r < 4; r++)
        dst[(size_t)r * 32] = (_Float16)((acc[nt][r] + bvv) * scl);
    } else {
      _Float16 h4[4];
#pragma unroll
      for (int r = 0; r < 4; r++) h4[r] = (_Float16)(acc[nt][r] + bvv);
      *(uint2*)&vt[((size_t)bb * 256 + n) * 400 + mi] = *(uint2*)h4;
    }
  }
}

// ---------------------------------------------------------------------------
// Fused attention v8: v6 structure (256 thr, 4 waves, grid 3200, LDS 13312)
// with ONE change: all 8 aw float4 loads per row-group are HOISTED into
// locals before any compute (v6 interleaved load->exp2, exposing 8 serial
// ~600cy L3 latencies per group -> 88us latency-bound plateau).
// Chunk-1 address is clamped (act ? m1 : m0) so all 8 loads are
// straight-line; z gets the act mask via a ternary (cndmask, no branch).
// launch_bounds(256,5): VGPR cap ~102 (need ~80: A 32 + e 16 + q 8 + addr).
// v7b's spill catastrophe (VGPR 84 requested ~160 -> 337MB spill WRITE) is
// avoided by this budget; spill markers (WRITE/FETCH/SGPR) must revert.
//   P1: S[16n][400m] = (Q*scl) @ K^T via 25 mfma_16x16x32_f16 -> LDS fp16
//   P2: one wave per row, 4 sequential row-groups; clustered loads; e in
//       f16 regs; 4 interleaved 6-step shfl_xor chains; packed-f16 pass 2.
//   P3b: O = S @ V, 13 chunks over 4 waves; cross-wave LDS reduce (8 KB).
// ---------------------------------------------------------------------------
#define SP 416  // S row pitch in halves (832 B, 16B-aligned); 13 chunks of 32

__global__ __launch_bounds__(256, 5) void attn_kernel(
    const _Float16* __restrict__ qh, const _Float16* __restrict__ kh,
    const _Float16* __restrict__ vt, const float* __restrict__ aw,
    float* __restrict__ scores, ushort* __restrict__ attnb) {
  __shared__ __align__(16) char smem[16 * SP * 2];  // 13312 B (Of needs 8192)
  __half* S = (__half*)smem;               // [16][SP] fp16

  int id = blockIdx.x;
  int c = ((id >> 6) << 3) | (id & 7);  // 0..399: (b, n-tile) combo
  int hh = (id >> 3) & 7;
  int b = c / 25;
  int n0 = (c - b * 25) * 16;

  int t = threadIdx.x;
  int w = t >> 6, l = t & 63;
  int lq = l >> 4, lr = l & 15;

  // ---- P1: S = (Q*scl) @ K^T (25 m-tiles over 4 waves) ----
  {
    const _Float16* qbase = qh + (((size_t)(b * 8 + hh)) * 400 + n0) * 32;
    const _Float16* kbase = kh + ((size_t)(b * 8 + hh)) * 400 * 32;
    f16x8 af = *(const f16x8*)(qbase + lr * 32 + lq * 8);
    for (int mt = w; mt < 25; mt += 4) {
      f16x8 bf = *(const f16x8*)(kbase + (size_t)(mt * 16 + lr) * 32 + lq * 8);
      f32x4 cc = {0.f, 0.f, 0.f, 0.f};
      cc = __builtin_amdgcn_mfma_f32_16x16x32_f16(af, bf, cc, 0, 0, 0);
#pragma unroll
      for (int r = 0; r < 4; r++)
        S[(lq * 4 + r) * SP + mt * 16 + lr] = __float2half(cc[r]);
    }
  }
  __syncthreads();

  // ---- P2: single aw sweep; clustered loads; one wave per row ----
  {
    int m0 = l * 4, m1 = 256 + l * 4;
    bool act = (l < 36);       // chunk1 covers m in [256,400) with 36 lanes
    int m1c = act ? m1 : m0;   // clamped: all lanes load a valid address
    const float* awb = aw + (((size_t)(b * 4)) * 400 + n0) * 400;
    float* scb = scores + (((size_t)(b * 8 + hh)) * 400 + n0) * 400;
#pragma unroll 1
    for (int g = 0; g < 4; g++) {
      int n = g * 4 + w;  // wave-private row: no intra-phase races
      _Float16* srow = (_Float16*)S + (size_t)n * SP;
      const float* awn = awb + (size_t)n * 400;
      float* scout = scb + (size_t)n * 400;

      // CLUSTERED: issue all 8 aw loads back-to-back (one vmcnt drain)
      float4 A0[4], A1[4];
#pragma unroll
      for (int i = 0; i < 4; i++)
        A0[i] = *(const float4*)(awn + (size_t)i * 160000 + m0);
#pragma unroll
      for (int i = 0; i < 4; i++)
        A1[i] = *(const float4*)(awn + (size_t)i * 160000 + m1c);

      // S (qk) values for both chunks
      f16x4 s0 = *(const f16x4*)(srow + m0);
      float q0[4], q1[4];
#pragma unroll
      for (int j = 0; j < 4; j++) q0[j] = (float)s0[j];
      if (act) {
        f16x4 s1 = *(const f16x4*)(srow + m1);
#pragma unroll
        for (int j = 0; j < 4; j++) q1[j] = (float)s1[j];
      } else {
#pragma unroll
        for (int j = 0; j < 4; j++) q1[j] = 0.f;
      }

      // pass 1: e = sign*exp2(|S*w|) packed f16, z[i] per-lane partials
      f16x4 e0[4], e1[4];
      float z[4];
#pragma unroll
      for (int i = 0; i < 4; i++) {
        float zz0 = 0.f, zz1 = 0.f;
#pragma unroll
        for (int j = 0; j < 4; j++) {
          float tt = q0[j] * ((const float*)&A0[i])[j];
          float ef = EXP2(fabsf(tt));
          zz0 += ef;
          e0[i][j] = (_Float16)copysignf(ef, tt);
        }
#pragma unroll
        for (int j = 0; j < 4; j++) {
          float tt = q1[j] * ((const float*)&A1[i])[j];
          float ef = EXP2(fabsf(tt));
          zz1 += ef;
          e1[i][j] = (_Float16)copysignf(ef, tt);
        }
        z[i] = zz0 + (act ? zz1 : 0.f);  // cndmask, no divergence
      }

      // 4 interleaved 6-step reduce chains over the full 64-lane wave
#pragma unroll
      for (int o = 1; o <= 32; o <<= 1) {
#pragma unroll
        for (int i = 0; i < 4; i++) z[i] += __shfl_xor(z[i], o);
      }

      // pass 2 (thread-local, packed f16): o = sum_i e[i]*zinv[i]
      f16x4 o0, o1;
#pragma unroll
      for (int j = 0; j < 4; j++) { o0[j] = (_Float16)0.f; o1[j] = (_Float16)0.f; }
#pragma unroll
      for (int i = 0; i < 4; i++) {
        _Float16 zh = (_Float16)(0.25f / (z[i] + 1e-10f));  // folds the /NW
        f16x4 zv = {zh, zh, zh, zh};
        o0 += e0[i] * zv;
        o1 += e1[i] * zv;
      }

      // writes: scores fp32 + S fp16 overwrite (+ zero-pad 400..415)
      float4 so;
#pragma unroll
      for (int j = 0; j < 4; j++) ((float*)&so)[j] = (float)o0[j];
      *(float4*)(scout + m0) = so;
      *(f16x4*)(srow + m0) = o0;
      if (act) {
        float4 s1o;
#pragma unroll
        for (int j = 0; j < 4; j++) ((float*)&s1o)[j] = (float)o1[j];
        *(float4*)(scout + m1) = s1o;
        *(f16x4*)(srow + m1) = o1;
      } else if (l < 40) {
        f16x4 hz;
#pragma unroll
        for (int j = 0; j < 4; j++) hz[j] = (_Float16)0.f;
        *(f16x4*)(srow + m1) = hz;  // zero-pad cols 400..415 for PV chunks
      }
    }
  }
  __syncthreads();

  // ---- P3b: O = S @ V (13 chunks of 32 m, split across 4 waves) ----
  const _Float16* vbase = vt + (((size_t)b) * 256 + hh * 32) * 400;
  f32x4 a0 = {0.f, 0.f, 0.f, 0.f}, a1 = {0.f, 0.f, 0.f, 0.f};
  const _Float16* Sh = (const _Float16*)S;
  for (int c2 = w; c2 < 13; c2 += 4) {
    f16x8 sf = *(const f16x8*)(Sh + lr * SP + c2 * 32 + lq * 8);
    f16x8 v0 = *(const f16x8*)(vbase + (size_t)lr * 400 + c2 * 32 + lq * 8);
    f16x8 v1 = *(const f16x8*)(vbase + (size_t)(16 + lr) * 400 + c2 * 32 + lq * 8);
    a0 = __builtin_amdgcn_mfma_f32_16x16x32_f16(sf, v0, a0, 0, 0, 0);
    a1 = __builtin_amdgcn_mfma_f32_16x16x32_f16(sf, v1, a1, 0, 0, 0);
  }
  __syncthreads();  // all S reads done before overwriting as float scratch
  float* Of = (float*)smem;  // [4w][16n][32d] = 8 KB
#pragma unroll
  for (int r = 0; r < 4; r++) {
    Of[(w * 16 + lq * 4 + r) * 32 + lr] = a0[r];
    Of[(w * 16 + lq * 4 + r) * 32 + 16 + lr] = a1[r];
  }
  __syncthreads();
  for (int o = t; o < 512; o += 256) {
    int n = o >> 5, d = o & 31;
    float s = Of[n * 32 + d] + Of[512 + n * 32 + d] +
              Of[1024 + n * 32 + d] + Of[1536 + n * 32 + d];
    attnb[((size_t)(b * 400 + n0 + n)) * 256 + hh * 32 + d] = f2b(s);
  }
}

// ---------------------------------------------------------------------------
// LayerNorm over last dim (256). One block per row.
// ---------------------------------------------------------------------------
__global__ __launch_bounds__(256) void ln_kernel(
    const float* __restrict__ src, const float* __restrict__ g,
    const float* __restrict__ be, float* __restrict__ outf,
    ushort* __restrict__ outb) {
  int row = blockIdx.x, t = threadIdx.x;
  float v = src[(size_t)row * 256 + t];
  __shared__ float red[4];
  float s = v;
#pragma unroll
  for (int o = 32; o > 0; o >>= 1) s += __shfl_down(s, o, 64);
  if ((t & 63) == 0) red[t >> 6] = s;
  __syncthreads();
  float mean = (red[0] + red[1] + red[2] + red[3]) * (1.f / 256.f);
  __syncthreads();
  float d = v - mean;
  s = d * d;
#pragma unroll
  for (int o = 32; o > 0; o >>= 1) s += __shfl_down(s, o, 64);
  if ((t & 63) == 0) red[t >> 6] = s;
  __syncthreads();
  float var = (red[0] + red[1] + red[2] + red[3]) * (1.f / 256.f);
  float y = d * rsqrtf(var + 1e-5f) * g[t] + be[t];
  outf[(size_t)row * 256 + t] = y;
  if (outb) outb[(size_t)row * 256 + t] = f2b(y);
}

// ---------------------------------------------------------------------------
extern "C" void kernel_launch(void* const* d_in, const int* in_sizes, int n_in,
                              void* d_out, int out_size, void* d_ws,
                              size_t ws_size, hipStream_t stream) {
  const float* x   = (const float*)d_in[0];
  const float* aw  = (const float*)d_in[1];
  const float* Wq  = (const float*)d_in[2];
  const float* bq  = (const float*)d_in[3];
  const float* Wk  = (const float*)d_in[4];
  const float* bk  = (const float*)d_in[5];
  const float* Wv  = (const float*)d_in[6];
  const float* bv  = (const float*)d_in[7];
  const float* Wo  = (const float*)d_in[8];
  const float* bo  = (const float*)d_in[9];
  const float* g1  = (const float*)d_in[10];
  const float* be1 = (const float*)d_in[11];
  const float* W1  = (const float*)d_in[12];
  const float* b1  = (const float*)d_in[13];
  const float* W2  = (const float*)d_in[14];
  const float* b2  = (const float*)d_in[15];
  const float* g2  = (const float*)d_in[16];
  const float* be2 = (const float*)d_in[17];

  if (ws_size < 34340864) return;  // scratch layout requirement

  char* ws = (char*)d_ws;
  ushort*   xb    = (ushort*)(ws + 0);          // 3,276,800
  ushort*   wqb   = (ushort*)(ws + 3276800);    //   131,072
  ushort*   wkb   = (ushort*)(ws + 3407872);
  ushort*   wvb   = (ushort*)(ws + 3538944);
  ushort*   wob   = (ushort*)(ws + 3670016);
  ushort*   w1b   = (ushort*)(ws + 3801088);    //   524,288
  ushort*   w2b   = (ushort*)(ws + 4325376);    //   524,288
  _Float16* qhb   = (_Float16*)(ws + 4849664);  // 3,276,800  [b][h][m][32]*scl
  _Float16* khb   = (_Float16*)(ws + 8126464);  //            [b][h][m][32]
  _Float16* vtb   = (_Float16*)(ws + 11403264); //            [b][d][m]
  ushort*   attnb = (ushort*)(ws + 14680064);
  float*    ao    = (float*)(ws + 17956864);    // 6,553,600 (reused as ffn2)
  float*    hbuf  = (float*)(ws + 24510464);    // 6,553,600
  ushort*   hb    = (ushort*)(ws + 31064064);   // 3,276,800 -> total 34,340,864
  ushort*   ffn1b = (ushort*)qhb;  // reuse q/k/v region, dead by then
  float*    ffn2  = ao;            // reuse ao, dead after LN1

  float* yout   = (float*)d_out;
  float* scores = yout + 1638400;

  convert_kernel<<<2368, 256, 0, stream>>>(x, Wq, Wk, Wv, Wo, W1, W2,
                                           xb, wqb, wkb, wvb, wob, w1b, w2b);
  qkv_gemm<<<dim3(4, 100, 3), 256, 0, stream>>>(
      xb, wqb, wkb, wvb, bq, bk, bv, qhb, khb, vtb);
  attn_kernel<<<3200, 256, 0, stream>>>(qhb, khb, vtb, aw, scores, attnb);
  gemm_bt<0, 1, 1, 0><<<dim3(4, 100), 256, 0, stream>>>(
      attnb, wob, bo, x, ao, nullptr, 6400, 256, 256);
  ln_kernel<<<6400, 256, 0, stream>>>(ao, g1, be1, hbuf, hb);
  gemm_bt<1, 0, 0, 1><<<dim3(16, 100), 256, 0, stream>>>(
      hb, w1b, b1, nullptr, nullptr, ffn1b, 6400, 1024, 256);
  gemm_bt<0, 1, 1, 0><<<dim3(4, 100), 256, 0, stream>>>(
      ffn1b, w2b, b2, hbuf, ffn2, nullptr, 6400, 256, 1024);
  ln_kernel<<<6400, 256, 0, stream>>>(ffn2, g2, be2, yout, nullptr);
}

// Round 8
// 250.365 us; speedup vs baseline: 1.5625x; 1.0074x over previous
//
#include <hip/hip_runtime.h>
#include <hip/hip_fp16.h>

typedef unsigned int uint32;

#define B_ 16
#define N_ 400
#define D_ 256
#define H_ 8
#define DH_ 32
#define NW_ 4

#if __has_builtin(__builtin_amdgcn_exp2f)
#define EXP2(x) __builtin_amdgcn_exp2f(x)
#else
#define EXP2(x) exp2f(x)
#endif

// log2(e)/sqrt(32): exp(|qk/sqrt(32) * w|) == exp2(|qk*SCL * w|)
#define QK_SCL 0.2550348f

using bf16x8 = __attribute__((ext_vector_type(8))) short;
using f16x8  = __attribute__((ext_vector_type(8))) _Float16;
using f16x4  = __attribute__((ext_vector_type(4))) _Float16;
using f32x4  = __attribute__((ext_vector_type(4))) float;

__device__ __forceinline__ ushort f2b(float f) {
  uint32 u = __float_as_uint(f);
  uint32 r = (u + 0x7fffu + ((u >> 16) & 1u)) >> 16;
  return (ushort)r;
}

// ---------------------------------------------------------------------------
// Convert fp32 inputs -> bf16 scratch copies (x + 6 weight matrices)
// ---------------------------------------------------------------------------
__global__ __launch_bounds__(256) void convert_kernel(
    const float* __restrict__ x,  const float* __restrict__ wq,
    const float* __restrict__ wk, const float* __restrict__ wv,
    const float* __restrict__ wo, const float* __restrict__ w1,
    const float* __restrict__ w2,
    ushort* __restrict__ xb,  ushort* __restrict__ wqb,
    ushort* __restrict__ wkb, ushort* __restrict__ wvb,
    ushort* __restrict__ wob, ushort* __restrict__ w1b,
    ushort* __restrict__ w2b) {
  int gid = blockIdx.x * 256 + threadIdx.x;   // unit = 4 floats
  const float* src; ushort* dst;
  if      (gid < 409600) { src = x;  dst = xb;  }
  else if ((gid -= 409600) < 16384) { src = wq; dst = wqb; }
  else if ((gid -= 16384) < 16384)  { src = wk; dst = wkb; }
  else if ((gid -= 16384) < 16384)  { src = wv; dst = wvb; }
  else if ((gid -= 16384) < 16384)  { src = wo; dst = wob; }
  else if ((gid -= 16384) < 65536)  { src = w1; dst = w1b; }
  else { gid -= 65536; src = w2; dst = w2b; }
  float4 f = ((const float4*)src)[gid];
  ushort4 u;
  u.x = f2b(f.x); u.y = f2b(f.y); u.z = f2b(f.z); u.w = f2b(f.w);
  *(ushort4*)&dst[(size_t)gid * 4] = u;
}

// ---------------------------------------------------------------------------
// Generic bf16 MFMA GEMM: C[M,N] = A[M,K] @ W[N,K]^T + bias, fused epilogue.
// 64x64 tile, 256 threads (4 waves), double-buffered LDS: 1 barrier / K-step.
// ---------------------------------------------------------------------------
template <int RELU, int RESID, int OUT_F32, int OUT_BF16>
__global__ __launch_bounds__(256) void gemm_bt(
    const ushort* __restrict__ A, const ushort* __restrict__ W,
    const float* __restrict__ bias, const float* __restrict__ resid,
    float* __restrict__ outf, ushort* __restrict__ outb,
    int M, int N, int K) {
  __shared__ __align__(16) ushort As[2][64 * 40];  // +8 bf16 pad per row
  __shared__ __align__(16) ushort Ws[2][64 * 40];
  int t = threadIdx.x;
  int l = t & 63, w = t >> 6;
  int n0 = blockIdx.x * 64, m0 = blockIdx.y * 64;
  int srow = t >> 2, sc = (t & 3) * 8;
  int lrow = l & 15, lk = (l >> 4) * 8;

  const uint4* ag = (const uint4*)&A[(size_t)(m0 + srow) * K + sc];
  const uint4* wg = (const uint4*)&W[(size_t)(n0 + srow) * K + sc];
  uint4 ar = ag[0], wr = wg[0];
  int nk = K >> 5;

  f32x4 acc[4];
#pragma unroll
  for (int nt = 0; nt < 4; nt++) acc[nt] = {0.f, 0.f, 0.f, 0.f};

  for (int kk = 0; kk < nk; kk++) {
    int cur = kk & 1;
    *(uint4*)&As[cur][srow * 40 + sc] = ar;
    *(uint4*)&Ws[cur][srow * 40 + sc] = wr;
    if (kk + 1 < nk) { ar = ag[(size_t)(kk + 1) * 4]; wr = wg[(size_t)(kk + 1) * 4]; }
    __syncthreads();
    bf16x8 af = *(const bf16x8*)&As[cur][(16 * w + lrow) * 40 + lk];
#pragma unroll
    for (int nt = 0; nt < 4; nt++) {
      bf16x8 bf = *(const bf16x8*)&Ws[cur][(nt * 16 + lrow) * 40 + lk];
      acc[nt] = __builtin_amdgcn_mfma_f32_16x16x32_bf16(af, bf, acc[nt], 0, 0, 0);
    }
  }

  // C/D layout: col = lane&15, row = (lane>>4)*4 + reg   [verified m89/m91]
#pragma unroll
  for (int nt = 0; nt < 4; nt++) {
    int n = n0 + nt * 16 + lrow;
    float bv = bias[n];
#pragma unroll
    for (int r = 0; r < 4; r++) {
      int m = m0 + 16 * w + (l >> 4) * 4 + r;
      float v = acc[nt][r] + bv;
      if (RELU)  v = fmaxf(v, 0.f);
      if (RESID) v += resid[(size_t)m * N + n];
      if (OUT_F32)  outf[(size_t)m * N + n] = v;
      if (OUT_BF16) outb[(size_t)m * N + n] = f2b(v);
    }
  }
}

// ---------------------------------------------------------------------------
// Fused QKV GEMM: one launch, z picks {q,k,v}. Same 64x64 MFMA core.
// q -> fp16 HEAD-MAJOR [b][h][m][32], pre-scaled by QK_SCL.
// k -> fp16 HEAD-MAJOR [b][h][m][32].
// v -> fp16 TRANSPOSED vt[b][d][m] (stride N_=400); d = h*32+dh.
// ---------------------------------------------------------------------------
__global__ __launch_bounds__(256) void qkv_gemm(
    const ushort* __restrict__ xb, const ushort* __restrict__ wq,
    const ushort* __restrict__ wk, const ushort* __restrict__ wv,
    const float* __restrict__ bq, const float* __restrict__ bk,
    const float* __restrict__ bv,
    _Float16* __restrict__ qh, _Float16* __restrict__ kh,
    _Float16* __restrict__ vt) {
  __shared__ __align__(16) ushort As[2][64 * 40];
  __shared__ __align__(16) ushort Ws[2][64 * 40];
  int z = blockIdx.z;
  const ushort* W = (z == 0) ? wq : (z == 1) ? wk : wv;
  const float* bias = (z == 0) ? bq : (z == 1) ? bk : bv;

  int t = threadIdx.x;
  int l = t & 63, w = t >> 6;
  int n0 = blockIdx.x * 64, m0 = blockIdx.y * 64;
  int srow = t >> 2, sc = (t & 3) * 8;
  int lrow = l & 15, lk = (l >> 4) * 8;

  const uint4* ag = (const uint4*)&xb[(size_t)(m0 + srow) * 256 + sc];
  const uint4* wg = (const uint4*)&W[(size_t)(n0 + srow) * 256 + sc];
  uint4 ar = ag[0], wr = wg[0];

  f32x4 acc[4];
#pragma unroll
  for (int nt = 0; nt < 4; nt++) acc[nt] = {0.f, 0.f, 0.f, 0.f};

  for (int kk = 0; kk < 8; kk++) {
    int cur = kk & 1;
    *(uint4*)&As[cur][srow * 40 + sc] = ar;
    *(uint4*)&Ws[cur][srow * 40 + sc] = wr;
    if (kk + 1 < 8) { ar = ag[(kk + 1) * 4]; wr = wg[(kk + 1) * 4]; }
    __syncthreads();
    bf16x8 af = *(const bf16x8*)&As[cur][(16 * w + lrow) * 40 + lk];
#pragma unroll
    for (int nt = 0; nt < 4; nt++) {
      bf16x8 bf = *(const bf16x8*)&Ws[cur][(nt * 16 + lrow) * 40 + lk];
      acc[nt] = __builtin_amdgcn_mfma_f32_16x16x32_bf16(af, bf, acc[nt], 0, 0, 0);
    }
  }

  int mb = m0 + 16 * w + (l >> 4) * 4;  // multiple of 4 -> never crosses b*400
  int bb = mb / 400;
  int mi = mb - bb * 400;
#pragma unroll
  for (int nt = 0; nt < 4; nt++) {
    int n = n0 + nt * 16 + lrow;
    float bvv = bias[n];
    if (z < 2) {
      _Float16* out = z ? kh : qh;
      float scl = z ? 1.f : QK_SCL;
      int hh = n >> 5, dd = n & 31;
      _Float16* dst = out + (((size_t)(bb * 8 + hh)) * 400 + mi) * 32 + dd;
#pragma unroll
      for (int r = 0; r < 4; r++)
        dst[(size_t)r * 32] = (_Float16)((acc[nt][r] + bvv) * scl);
    } else {
      _Float16 h4[4];
#pragma unroll
      for (int r = 0; r < 4; r++) h4[r] = (_Float16)(acc[nt][r] + bvv);
      *(uint2*)&vt[((size_t)bb * 256 + n) * 400 + mi] = *(uint2*)h4;
    }
  }
}

// ---------------------------------------------------------------------------
// Fused attention v9: v8 + ONE-GROUP-AHEAD aw PREFETCH (double buffer).
// v8 clustered the 8 aw loads but issued them right before use: each of the
// 4 row-groups still pays one ~600cy L2/L3 round trip at its head, and at
// ~4 waves/SIMD that stall isn't covered (VALUBusy stuck at 46%, wall 66us
// vs ~30us VALU-busy). v9 issues group g+1's 8 loads at the TOP of group g
// (aw regs are dead after pass-1), giving them ~1000cy of exp2/reduce/pass2
// to complete. Buffers are explicitly named A/B pairs (compile-time
// indexing only — rule #20) passed by reference to the group body.
// Budget: peak ~114 VGPR (64 buf + 16 e + 8 q + addr/misc);
// launch_bounds(256,4) caps at 128 -> same 16 waves/CU as v8 measured.
// Spill tripwires: SGPR~32, WRITE~83MB, FETCH~48MB must be unchanged.
//   P1: S[16n][400m] = (Q*scl) @ K^T via 25 mfma_16x16x32_f16 -> LDS fp16
//   P2: one wave per row, 4 row-groups, prefetched double-buffered aw;
//       e in f16 regs; 4 interleaved 6-step shfl_xor chains; packed pass 2.
//   P3b: O = S @ V, 13 chunks over 4 waves; cross-wave LDS reduce (8 KB).
// ---------------------------------------------------------------------------
#define SP 416  // S row pitch in halves (832 B, 16B-aligned); 13 chunks of 32

__global__ __launch_bounds__(256, 4) void attn_kernel(
    const _Float16* __restrict__ qh, const _Float16* __restrict__ kh,
    const _Float16* __restrict__ vt, const float* __restrict__ aw,
    float* __restrict__ scores, ushort* __restrict__ attnb) {
  __shared__ __align__(16) char smem[16 * SP * 2];  // 13312 B (Of needs 8192)
  __half* S = (__half*)smem;               // [16][SP] fp16

  int id = blockIdx.x;
  int c = ((id >> 6) << 3) | (id & 7);  // 0..399: (b, n-tile) combo
  int hh = (id >> 3) & 7;
  int b = c / 25;
  int n0 = (c - b * 25) * 16;

  int t = threadIdx.x;
  int w = t >> 6, l = t & 63;
  int lq = l >> 4, lr = l & 15;

  // ---- P1: S = (Q*scl) @ K^T (25 m-tiles over 4 waves) ----
  {
    const _Float16* qbase = qh + (((size_t)(b * 8 + hh)) * 400 + n0) * 32;
    const _Float16* kbase = kh + ((size_t)(b * 8 + hh)) * 400 * 32;
    f16x8 af = *(const f16x8*)(qbase + lr * 32 + lq * 8);
    for (int mt = w; mt < 25; mt += 4) {
      f16x8 bf = *(const f16x8*)(kbase + (size_t)(mt * 16 + lr) * 32 + lq * 8);
      f32x4 cc = {0.f, 0.f, 0.f, 0.f};
      cc = __builtin_amdgcn_mfma_f32_16x16x32_f16(af, bf, cc, 0, 0, 0);
#pragma unroll
      for (int r = 0; r < 4; r++)
        S[(lq * 4 + r) * SP + mt * 16 + lr] = __float2half(cc[r]);
    }
  }
  __syncthreads();

  // ---- P2: single aw sweep; double-buffered 1-group-ahead prefetch ----
  {
    int m0 = l * 4, m1 = 256 + l * 4;
    bool act = (l < 36);       // chunk1 covers m in [256,400) with 36 lanes
    int m1c = act ? m1 : m0;   // clamped: all lanes load a valid address
    const float* awb = aw + (((size_t)(b * 4)) * 400 + n0) * 400;
    float* scb = scores + (((size_t)(b * 8 + hh)) * 400 + n0) * 400;

    float4 A0[4], A1[4], B0[4], B1[4];
    {
      const float* awn = awb + (size_t)w * 400;  // group 0 row
#pragma unroll
      for (int i = 0; i < 4; i++) {
        A0[i] = *(const float4*)(awn + (size_t)i * 160000 + m0);
        A1[i] = *(const float4*)(awn + (size_t)i * 160000 + m1c);
      }
    }

    auto grp = [&](int n, float4 (&c0)[4], float4 (&c1)[4],
                   float4 (&p0)[4], float4 (&p1)[4], bool pf) {
      // issue NEXT group's loads first: they complete under this group's
      // compute (c0/c1 are dead after pass 1, so peak live = c + p briefly)
      if (pf) {
        const float* awn = awb + (size_t)(n + 4) * 400;
#pragma unroll
        for (int i = 0; i < 4; i++) {
          p0[i] = *(const float4*)(awn + (size_t)i * 160000 + m0);
          p1[i] = *(const float4*)(awn + (size_t)i * 160000 + m1c);
        }
      }
      _Float16* srow = (_Float16*)S + (size_t)n * SP;
      float* scout = scb + (size_t)n * 400;

      // S (qk) values for both chunks
      f16x4 s0 = *(const f16x4*)(srow + m0);
      float q0[4], q1[4];
#pragma unroll
      for (int j = 0; j < 4; j++) q0[j] = (float)s0[j];
      if (act) {
        f16x4 s1 = *(const f16x4*)(srow + m1);
#pragma unroll
        for (int j = 0; j < 4; j++) q1[j] = (float)s1[j];
      } else {
#pragma unroll
        for (int j = 0; j < 4; j++) q1[j] = 0.f;
      }

      // pass 1: e = sign*exp2(|S*w|) packed f16, z[i] per-lane partials
      f16x4 e0[4], e1[4];
      float z[4];
#pragma unroll
      for (int i = 0; i < 4; i++) {
        float zz0 = 0.f, zz1 = 0.f;
#pragma unroll
        for (int j = 0; j < 4; j++) {
          float tt = q0[j] * ((const float*)&c0[i])[j];
          float ef = EXP2(fabsf(tt));
          zz0 += ef;
          e0[i][j] = (_Float16)copysignf(ef, tt);
        }
#pragma unroll
        for (int j = 0; j < 4; j++) {
          float tt = q1[j] * ((const float*)&c1[i])[j];
          float ef = EXP2(fabsf(tt));
          zz1 += ef;
          e1[i][j] = (_Float16)copysignf(ef, tt);
        }
        z[i] = zz0 + (act ? zz1 : 0.f);  // cndmask, no divergence
      }

      // 4 interleaved 6-step reduce chains over the full 64-lane wave
#pragma unroll
      for (int o = 1; o <= 32; o <<= 1) {
#pragma unroll
        for (int i = 0; i < 4; i++) z[i] += __shfl_xor(z[i], o);
      }

      // pass 2 (thread-local, packed f16): o = sum_i e[i]*zinv[i]
      f16x4 o0, o1;
#pragma unroll
      for (int j = 0; j < 4; j++) { o0[j] = (_Float16)0.f; o1[j] = (_Float16)0.f; }
#pragma unroll
      for (int i = 0; i < 4; i++) {
        _Float16 zh = (_Float16)(0.25f / (z[i] + 1e-10f));  // folds the /NW
        f16x4 zv = {zh, zh, zh, zh};
        o0 += e0[i] * zv;
        o1 += e1[i] * zv;
      }

      // writes: scores fp32 + S fp16 overwrite (+ zero-pad 400..415)
      float4 so;
#pragma unroll
      for (int j = 0; j < 4; j++) ((float*)&so)[j] = (float)o0[j];
      *(float4*)(scout + m0) = so;
      *(f16x4*)(srow + m0) = o0;
      if (act) {
        float4 s1o;
#pragma unroll
        for (int j = 0; j < 4; j++) ((float*)&s1o)[j] = (float)o1[j];
        *(float4*)(scout + m1) = s1o;
        *(f16x4*)(srow + m1) = o1;
      } else if (l < 40) {
        f16x4 hz;
#pragma unroll
        for (int j = 0; j < 4; j++) hz[j] = (_Float16)0.f;
        *(f16x4*)(srow + m1) = hz;  // zero-pad cols 400..415 for PV chunks
      }
    };

    // wave-private rows n = g*4 + w; explicit A/B alternation (no runtime
    // buffer indexing -> stays in registers)
    grp(w,      A0, A1, B0, B1, true);
    grp(4 + w,  B0, B1, A0, A1, true);
    grp(8 + w,  A0, A1, B0, B1, true);
    grp(12 + w, B0, B1, A0, A1, false);
  }
  __syncthreads();

  // ---- P3b: O = S @ V (13 chunks of 32 m, split across 4 waves) ----
  const _Float16* vbase = vt + (((size_t)b) * 256 + hh * 32) * 400;
  f32x4 a0 = {0.f, 0.f, 0.f, 0.f}, a1 = {0.f, 0.f, 0.f, 0.f};
  const _Float16* Sh = (const _Float16*)S;
  for (int c2 = w; c2 < 13; c2 += 4) {
    f16x8 sf = *(const f16x8*)(Sh + lr * SP + c2 * 32 + lq * 8);
    f16x8 v0 = *(const f16x8*)(vbase + (size_t)lr * 400 + c2 * 32 + lq * 8);
    f16x8 v1 = *(const f16x8*)(vbase + (size_t)(16 + lr) * 400 + c2 * 32 + lq * 8);
    a0 = __builtin_amdgcn_mfma_f32_16x16x32_f16(sf, v0, a0, 0, 0, 0);
    a1 = __builtin_amdgcn_mfma_f32_16x16x32_f16(sf, v1, a1, 0, 0, 0);
  }
  __syncthreads();  // all S reads done before overwriting as float scratch
  float* Of = (float*)smem;  // [4w][16n][32d] = 8 KB
#pragma unroll
  for (int r = 0; r < 4; r++) {
    Of[(w * 16 + lq * 4 + r) * 32 + lr] = a0[r];
    Of[(w * 16 + lq * 4 + r) * 32 + 16 + lr] = a1[r];
  }
  __syncthreads();
  for (int o = t; o < 512; o += 256) {
    int n = o >> 5, d = o & 31;
    float s = Of[n * 32 + d] + Of[512 + n * 32 + d] +
              Of[1024 + n * 32 + d] + Of[1536 + n * 32 + d];
    attnb[((size_t)(b * 400 + n0 + n)) * 256 + hh * 32 + d] = f2b(s);
  }
}

// ---------------------------------------------------------------------------
// LayerNorm over last dim (256). One block per row.
// ---------------------------------------------------------------------------
__global__ __launch_bounds__(256) void ln_kernel(
    const float* __restrict__ src, const float* __restrict__ g,
    const float* __restrict__ be, float* __restrict__ outf,
    ushort* __restrict__ outb) {
  int row = blockIdx.x, t = threadIdx.x;
  float v = src[(size_t)row * 256 + t];
  __shared__ float red[4];
  float s = v;
#pragma unroll
  for (int o = 32; o > 0; o >>= 1) s += __shfl_down(s, o, 64);
  if ((t & 63) == 0) red[t >> 6] = s;
  __syncthreads();
  float mean = (red[0] + red[1] + red[2] + red[3]) * (1.f / 256.f);
  __syncthreads();
  float d = v - mean;
  s = d * d;
#pragma unroll
  for (int o = 32; o > 0; o >>= 1) s += __shfl_down(s, o, 64);
  if ((t & 63) == 0) red[t >> 6] = s;
  __syncthreads();
  float var = (red[0] + red[1] + red[2] + red[3]) * (1.f / 256.f);
  float y = d * rsqrtf(var + 1e-5f) * g[t] + be[t];
  outf[(size_t)row * 256 + t] = y;
  if (outb) outb[(size_t)row * 256 + t] = f2b(y);
}

// ---------------------------------------------------------------------------
extern "C" void kernel_launch(void* const* d_in, const int* in_sizes, int n_in,
                              void* d_out, int out_size, void* d_ws,
                              size_t ws_size, hipStream_t stream) {
  const float* x   = (const float*)d_in[0];
  const float* aw  = (const float*)d_in[1];
  const float* Wq  = (const float*)d_in[2];
  const float* bq  = (const float*)d_in[3];
  const float* Wk  = (const float*)d_in[4];
  const float* bk  = (const float*)d_in[5];
  const float* Wv  = (const float*)d_in[6];
  const float* bv  = (const float*)d_in[7];
  const float* Wo  = (const float*)d_in[8];
  const float* bo  = (const float*)d_in[9];
  const float* g1  = (const float*)d_in[10];
  const float* be1 = (const float*)d_in[11];
  const float* W1  = (const float*)d_in[12];
  const float* b1  = (const float*)d_in[13];
  const float* W2  = (const float*)d_in[14];
  const float* b2  = (const float*)d_in[15];
  const float* g2  = (const float*)d_in[16];
  const float* be2 = (const float*)d_in[17];

  if (ws_size < 34340864) return;  // scratch layout requirement

  char* ws = (char*)d_ws;
  ushort*   xb    = (ushort*)(ws + 0);          // 3,276,800
  ushort*   wqb   = (ushort*)(ws + 3276800);    //   131,072
  ushort*   wkb   = (ushort*)(ws + 3407872);
  ushort*   wvb   = (ushort*)(ws + 3538944);
  ushort*   wob   = (ushort*)(ws + 3670016);
  ushort*   w1b   = (ushort*)(ws + 3801088);    //   524,288
  ushort*   w2b   = (ushort*)(ws + 4325376);    //   524,288
  _Float16* qhb   = (_Float16*)(ws + 4849664);  // 3,276,800  [b][h][m][32]*scl
  _Float16* khb   = (_Float16*)(ws + 8126464);  //            [b][h][m][32]
  _Float16* vtb   = (_Float16*)(ws + 11403264); //            [b][d][m]
  ushort*   attnb = (ushort*)(ws + 14680064);
  float*    ao    = (float*)(ws + 17956864);    // 6,553,600 (reused as ffn2)
  float*    hbuf  = (float*)(ws + 24510464);    // 6,553,600
  ushort*   hb    = (ushort*)(ws + 31064064);   // 3,276,800 -> total 34,340,864
  ushort*   ffn1b = (ushort*)qhb;  // reuse q/k/v region, dead by then
  float*    ffn2  = ao;            // reuse ao, dead after LN1

  float* yout   = (float*)d_out;
  float* scores = yout + 1638400;

  convert_kernel<<<2368, 256, 0, stream>>>(x, Wq, Wk, Wv, Wo, W1, W2,
                                           xb, wqb, wkb, wvb, wob, w1b, w2b);
  qkv_gemm<<<dim3(4, 100, 3), 256, 0, stream>>>(
      xb, wqb, wkb, wvb, bq, bk, bv, qhb, khb, vtb);
  attn_kernel<<<3200, 256, 0, stream>>>(qhb, khb, vtb, aw, scores, attnb);
  gemm_bt<0, 1, 1, 0><<<dim3(4, 100), 256, 0, stream>>>(
      attnb, wob, bo, x, ao, nullptr, 6400, 256, 256);
  ln_kernel<<<6400, 256, 0, stream>>>(ao, g1, be1, hbuf, hb);
  gemm_bt<1, 0, 0, 1><<<dim3(16, 100), 256, 0, stream>>>(
      hb, w1b, b1, nullptr, nullptr, ffn1b, 6400, 1024, 256);
  gemm_bt<0, 1, 1, 0><<<dim3(4, 100), 256, 0, stream>>>(
      ffn1b, w2b, b2, hbuf, ffn2, nullptr, 6400, 256, 1024);
  ln_kernel<<<6400, 256, 0, stream>>>(ffn2, g2, be2, yout, nullptr);
}